// Round 1
// baseline (1525.830 us; speedup 1.0000x reference)
//
#include <hip/hip_runtime.h>

// 3D VALID conv: x(2,32,64,64,64) f32, W(64,32,3,3,3) f32 -> out(2,64,62,62,62) f32
// Block = 256 threads = 64 w-lanes x 4 h-rows.
// Each block: fixed (b, d, h-tile of 4, oc-group of 16). Loop over 4 ic-chunks of 8,
// staging x[8ic][3z][6y][64x] in LDS; W read with block-uniform indices (-> s_load).

#define IC_ALL 32
#define OC_ALL 64
#define DIN 64
#define DOUT 62

__global__ __launch_bounds__(256, 2) void conv3d_f32_direct(
    const float* __restrict__ x, const float* __restrict__ W,
    float* __restrict__ out)
{
    // pad last dim 64 -> 66 so reads at [lane+kx] (max 65) stay in-bounds
    __shared__ float xs[8][3][6][66];   // 38016 B

    const int tid  = threadIdx.x;
    const int lane = tid & 63;   // w
    const int row  = tid >> 6;   // 0..3  (h within tile)

    int bid = blockIdx.x;
    const int ocg = bid & 3;  bid >>= 2;   // 4 groups of 16 oc
    const int ht  = bid & 15; bid >>= 4;   // 16 tiles of 4 h-rows
    const int d   = bid % DOUT;
    const int b   = bid / DOUT;

    const int h0  = ht * 4;
    const int oc0 = ocg * 16;

    float acc[16];
#pragma unroll
    for (int o = 0; o < 16; ++o) acc[o] = 0.f;

    for (int icc = 0; icc < 4; ++icc) {
        __syncthreads();   // protect previous chunk's readers
        // stage 8*3*6*64 = 9216 elements
        for (int idx = tid; idx < 8 * 3 * 6 * 64; idx += 256) {
            int xw = idx & 63;
            int r  = idx >> 6;      // 0..143
            int y  = r % 6;
            r /= 6;                 // 0..23
            int z  = r % 3;
            int ic = r / 3;         // 0..7
            int gy = h0 + y; if (gy > 63) gy = 63;   // clamp: clamped rows feed only discarded outputs
            xs[ic][z][y][xw] =
                x[(((size_t)(b * IC_ALL + icc * 8 + ic) * DIN + (d + z)) * DIN + gy) * DIN + xw];
        }
        __syncthreads();

        for (int ic = 0; ic < 8; ++ic) {
            const float* wp0 = W + ((size_t)oc0 * IC_ALL + (icc * 8 + ic)) * 27;
#pragma unroll
            for (int kz = 0; kz < 3; ++kz)
#pragma unroll
            for (int ky = 0; ky < 3; ++ky)
#pragma unroll
            for (int kx = 0; kx < 3; ++kx) {
                float xv = xs[ic][kz][row + ky][lane + kx];
                const float* wp = wp0 + kz * 9 + ky * 3 + kx;
#pragma unroll
                for (int o = 0; o < 16; ++o)
                    acc[o] = fmaf(xv, wp[(size_t)o * IC_ALL * 27], acc[o]);
            }
        }
    }

    const int h = h0 + row;
    const int w = lane;
    if (h < DOUT && w < DOUT) {
        size_t ob = ((((size_t)b * OC_ALL + oc0) * DOUT + d) * DOUT + h) * DOUT + w;
#pragma unroll
        for (int o = 0; o < 16; ++o)
            out[ob + (size_t)o * DOUT * DOUT * DOUT] = acc[o];
    }
}

extern "C" void kernel_launch(void* const* d_in, const int* in_sizes, int n_in,
                              void* d_out, int out_size, void* d_ws, size_t ws_size,
                              hipStream_t stream) {
    const float* x = (const float*)d_in[0];
    const float* W = (const float*)d_in[1];
    float* out = (float*)d_out;

    // grid = b(2) * d(62) * ht(16) * ocg(4) = 7936 blocks
    dim3 grid(2 * DOUT * 16 * 4);
    conv3d_f32_direct<<<grid, 256, 0, stream>>>(x, W, out);
}

// Round 2
// 108.263 us; speedup vs baseline: 14.0937x; 14.0937x over previous
//
#include <hip/hip_runtime.h>
#include <hip/hip_bf16.h>

#define DIN 64
#define DOUT 62
#define ICH 32
#define OCH 64

typedef __bf16 bf16x8 __attribute__((ext_vector_type(8)));
typedef float f32x4 __attribute__((ext_vector_type(4)));

// ---------- prep: W[oc][ic][kz][ky][kx] f32 -> Wre[tap][oc][ic] bf16(ushort) ----------
__global__ void prep_w(const float* __restrict__ W, unsigned short* __restrict__ Wre) {
    int idx = blockIdx.x * 256 + threadIdx.x;        // 27*64*32 = 55296
    if (idx >= 27 * OCH * ICH) return;
    int ic  = idx & 31;
    int oc  = (idx >> 5) & 63;
    int tap = idx >> 11;
    float v = W[((size_t)oc * ICH + ic) * 27 + tap];
    Wre[idx] = __builtin_bit_cast(unsigned short, (__bf16)v);
}

// ---------- main: implicit GEMM, 27 taps x mfma_16x16x32_bf16 ----------
// block tile: (b, d, 4 h-rows) x 64 oc x 64 w.  wave = one h row.
// LDS x: [z(3)][y(6)][w(66)][4 slots of 16B(8 ic bf16)], slot = icg ^ ((w>>1)&3)
template<bool USE_WRE>
__global__ __launch_bounds__(256, 2) void conv3d_mfma(
    const float* __restrict__ x, const float* __restrict__ W,
    const unsigned short* __restrict__ Wre, float* __restrict__ out)
{
    __shared__ int4 xs4[3 * 6 * 66 * 4];             // 76,032 B
    char* xs = (char*)xs4;

    const int tid  = threadIdx.x;
    const int lane = tid & 63;
    const int wave = tid >> 6;

    int bid = blockIdx.x;
    const int ht = bid & 15; bid >>= 4;
    const int d  = bid % DOUT;
    const int b  = bid / DOUT;
    const int h0 = ht * 4;

    // ---- stage x: thread (wave=icg, lane=w) packs 8 ic -> one b128 per (z,y) ----
    {
        const int icg = wave;                        // 8 ic per group
        const int w   = lane;
        const int slot = icg ^ ((w >> 1) & 3);
        for (int z = 0; z < 3; ++z) {
            for (int y = 0; y < 6; ++y) {
                int gy = h0 + y; if (gy > 63) gy = 63;   // clamped rows feed only h>=62 (discarded)
                const float* xp = x + (((size_t)(b * ICH + icg * 8) * DIN + (d + z)) * DIN + gy) * DIN + w;
                bf16x8 pk;
#pragma unroll
                for (int j = 0; j < 8; ++j)
                    pk[j] = (__bf16)xp[(size_t)j * DIN * DIN * DIN];
                *(int4*)(xs + (((z * 6 + y) * 66 + w) * 64 + slot * 16)) = __builtin_bit_cast(int4, pk);
            }
        }
        // zero-fill w = 64,65 (feeds only w>=62 outputs, but keep NaN-free)
        if (tid < 144) {
            int z = tid / 48, r = tid % 48, y = r / 8, q = r % 8;
            int w2 = 64 + (q >> 2), icg2 = q & 3;
            int sl = icg2 ^ ((w2 >> 1) & 3);
            *(int4*)(xs + (((z * 6 + y) * 66 + w2) * 64 + sl * 16)) = int4{0, 0, 0, 0};
        }
    }
    __syncthreads();

    const int wlo = lane & 15;                       // w-in-tile / oc-in-tile
    const int whi = lane >> 4;                       // k-group (8 ic)
    const int row = wave;                            // h row

    f32x4 acc[4][4];                                 // [mt=oc-tile][nt=w-tile]
#pragma unroll
    for (int mt = 0; mt < 4; ++mt)
#pragma unroll
        for (int nt = 0; nt < 4; ++nt)
            acc[mt][nt] = f32x4{0.f, 0.f, 0.f, 0.f};

    for (int kz = 0; kz < 3; ++kz) {
#pragma unroll
        for (int ky = 0; ky < 3; ++ky) {
#pragma unroll
            for (int kx = 0; kx < 3; ++kx) {
                const int tap = (kz * 3 + ky) * 3 + kx;
                // A fragments: W rows (oc), k = whi*8 + j
                bf16x8 af[4];
                if (USE_WRE) {
                    const char* wp = (const char*)Wre + (size_t)tap * (OCH * ICH * 2) + whi * 16;
#pragma unroll
                    for (int mt = 0; mt < 4; ++mt) {
                        int oc = mt * 16 + wlo;
                        af[mt] = __builtin_bit_cast(bf16x8, *(const int4*)(wp + oc * 64));
                    }
                } else {
#pragma unroll
                    for (int mt = 0; mt < 4; ++mt) {
                        int oc = mt * 16 + wlo;
                        const float* wp = W + ((size_t)oc * ICH + whi * 8) * 27 + tap;
                        bf16x8 t;
#pragma unroll
                        for (int j = 0; j < 8; ++j) t[j] = (__bf16)wp[j * 27];
                        af[mt] = t;
                    }
                }
                // B fragments: x cols (w), k = whi*8 + j  (one ds_read_b128 each)
                bf16x8 bfr[4];
#pragma unroll
                for (int nt = 0; nt < 4; ++nt) {
                    int w = nt * 16 + wlo + kx;
                    int slot = whi ^ ((w >> 1) & 3);
                    const char* p = xs + ((((kz * 6 + row + ky) * 66) + w) * 64 + slot * 16);
                    bfr[nt] = __builtin_bit_cast(bf16x8, *(const int4*)p);
                }
#pragma unroll
                for (int mt = 0; mt < 4; ++mt)
#pragma unroll
                    for (int nt = 0; nt < 4; ++nt)
                        acc[mt][nt] = __builtin_amdgcn_mfma_f32_16x16x32_bf16(
                            af[mt], bfr[nt], acc[mt][nt], 0, 0, 0);
            }
        }
    }

    // ---- store: D row=(l>>4)*4+r -> oc, col=l&15 -> w ----
    const int h = h0 + row;
    if (h < DOUT) {
#pragma unroll
        for (int mt = 0; mt < 4; ++mt) {
#pragma unroll
            for (int r = 0; r < 4; ++r) {
                int oc = mt * 16 + whi * 4 + r;
                size_t ob = ((((size_t)b * OCH + oc) * DOUT + d) * DOUT + h) * DOUT;
#pragma unroll
                for (int nt = 0; nt < 4; ++nt) {
                    int w = nt * 16 + wlo;
                    if (w < DOUT) out[ob + w] = acc[mt][nt][r];
                }
            }
        }
    }
}

extern "C" void kernel_launch(void* const* d_in, const int* in_sizes, int n_in,
                              void* d_out, int out_size, void* d_ws, size_t ws_size,
                              hipStream_t stream) {
    const float* x = (const float*)d_in[0];
    const float* W = (const float*)d_in[1];
    float* out = (float*)d_out;

    const dim3 grid(2 * DOUT * 16);                  // b * d * h-tiles = 1984
    const size_t wre_bytes = (size_t)27 * OCH * ICH * 2;

    if (ws_size >= wre_bytes) {
        unsigned short* Wre = (unsigned short*)d_ws;
        prep_w<<<dim3((27 * OCH * ICH + 255) / 256), 256, 0, stream>>>(W, Wre);
        conv3d_mfma<true><<<grid, 256, 0, stream>>>(x, W, Wre, out);
    } else {
        conv3d_mfma<false><<<grid, 256, 0, stream>>>(x, W, nullptr, out);
    }
}